// Round 3
// baseline (302.664 us; speedup 1.0000x reference)
//
#include <hip/hip_runtime.h>

// Problem constants (from reference)
#define B_ 2048
#define S_ 200
#define D_ 128
#define H_ 64
#define KB_ 8                  // batches per persistent block
#define GRID_ (B_ / KB_)       // 256 blocks = 1 per CU (LDS-forced)
#define MASK_SCALE 1e10f

typedef __attribute__((ext_vector_type(8))) short short8_t;            // 8 bf16 in 4 VGPRs
typedef __attribute__((ext_vector_type(4))) float f32x4;
typedef __attribute__((ext_vector_type(4))) unsigned short ushort4_t;  // 8B

__device__ __forceinline__ unsigned short f2bf(float f) {
    unsigned u = __float_as_uint(f);
    unsigned r = (u + 0x7fffu + ((u >> 16) & 1u)) >> 16;   // round-to-nearest-even
    return (unsigned short)r;
}
__device__ __forceinline__ float bf2f(unsigned short v) {
    return __uint_as_float(((unsigned)v) << 16);
}
// packed f32x2 -> bf16x2, RNE, 1 instruction
__device__ __forceinline__ unsigned cvt_pk_bf16(float lo, float hi) {
    unsigned r;
    asm("v_cvt_pk_bf16_f32 %0, %1, %2" : "=v"(r) : "v"(lo), "v"(hi));
    return r;
}
// Barrier that does NOT drain vmcnt: lets prefetch loads stay in flight.
__device__ __forceinline__ void bar() {
    asm volatile("s_waitcnt lgkmcnt(0)\n\ts_barrier" ::: "memory");
}

// ---------------------------------------------------------------------------
// Single persistent fused kernel: 256 blocks x 512 threads, 8 batches each,
// double-buffered his tile (2 x 51.2 KB, XOR-swizzled bf16).
//
// Prologue (all hidden under the batch-0 HBM stream, ~10K cycles):
//   issue batch-0 his loads -> load all of W (98 KB, coalesced; thread t holds
//   W1/W2/W3 float4s at the SAME flat offset so w1+w2 / w3-w2 are local) ->
//   stage wfrag (16 KB bf16, MFMA B-frag order) + w23t (32 KB f32 [h][d]) into
//   the FREE second his buffer -> barrier -> read persistent bfrag/wsl regs.
//   This replaces the old separate `prep` dispatch + its launch gap.
//
// Steady state per iteration: issue next batch's loads (pinned early via
// sched_barrier), MFMA alpha + softmax + pool current buffer while loads are
// in flight across the raw (non-vmcnt-draining) barriers, then convert +
// ds_write next buffer + next tproj partials.
// ---------------------------------------------------------------------------
__global__ __launch_bounds__(512, 2) void fused_kernel(const float* __restrict__ his,
                                                       const float* __restrict__ mask,
                                                       const float* __restrict__ target,
                                                       const float* __restrict__ W,
                                                       const float* __restrict__ W_bias,
                                                       const float* __restrict__ Ovec,
                                                       float* __restrict__ out) {
    __shared__ unsigned short hisb[2][S_ * D_];     // 2 x 51,200 B, swizzled
    __shared__ float alph[208];                     // raw alpha (13 tiles x 16)
    __shared__ float attw[208];                     // exp(a - m), unnormalized
    __shared__ float red8[8];                       // per-wave max
    __shared__ float red8b[8];                      // per-wave expsum
    __shared__ float ov_s[H_];
    __shared__ float tpp[8 * H_];                   // tproj partials [wave][h]
    __shared__ float pool_s[7 * D_];                // pooling cross-wave partials

    const int t    = threadIdx.x;
    const int lane = t & 63;
    const int wv   = t >> 6;       // 0..7
    const int lm   = lane & 15;
    const int q    = lane >> 4;
    const int b0   = blockIdx.x * KB_;

    if (t < H_) ov_s[t] = Ovec[t];
    const float wb = (wv == 0) ? W_bias[lane] : 0.f;

    short8_t bfrag[16];            // persistent MFMA B fragments (64 VGPR)
    float4 wsl[4];                 // persistent (W3-W2)^T[h=lane][d=wv*16..+15]
    float mk;

    // ================= prologue =================
    {
        // (1) batch-0 his stream FIRST (starts the HBM pipe)
        const float4* hb4 = (const float4*)(his + (size_t)b0 * S_ * D_);
        float4 x0[13];
        #pragma unroll
        for (int j = 0; j < 13; ++j) {
            int i = t + j * 512;
            if (i < 6400) x0[j] = hb4[i];
        }
        // (2) W loads: thread t holds W1/W2/W3 at flat float4 index t+k*512
        const float4* W4 = (const float4*)W;
        float4 w1v[4], w2v[4], w3v[4];
        #pragma unroll
        for (int k = 0; k < 4; ++k) {
            int j = t + k * 512;
            w1v[k] = W4[j];
            w2v[k] = W4[j + 2048];
            w3v[k] = W4[j + 4096];
        }
        mk = (t < S_) ? mask[(size_t)b0 * S_ + t] : 0.f;
        const float4* tg4 = (const float4*)(target + (size_t)b0 * D_) + wv * 4;
        float4 tg0[4];
        #pragma unroll
        for (int k = 0; k < 4; ++k) tg0[k] = tg4[k];
        __builtin_amdgcn_sched_barrier(0);   // all loads issued before compute

        // (3) stage W-derived data into the free second his buffer
        unsigned short* wf_s = hisb[1];                      // 16 KB bf16, frag order
        float* wdt_s = (float*)((char*)hisb[1] + 16384);     // 32 KB f32 [h][128]
        #pragma unroll
        for (int k = 0; k < 4; ++k) {
            int j = t + k * 512;
            int e = 4 * j;
            int d = e >> 6;          // 0..127
            int h = e & 63;          // multiple of 4
            float whc[4] = { w1v[k].x + w2v[k].x, w1v[k].y + w2v[k].y,
                             w1v[k].z + w2v[k].z, w1v[k].w + w2v[k].w };
            float wdc[4] = { w3v[k].x - w2v[k].x, w3v[k].y - w2v[k].y,
                             w3v[k].z - w2v[k].z, w3v[k].w - w2v[k].w };
            int kt = d >> 5, qd = (d >> 3) & 3, jj = d & 7;
            #pragma unroll
            for (int c = 0; c < 4; ++c) {
                int hh = h + c;
                int nt = hh >> 4, lmh = hh & 15;
                int ln = (qd << 4) | lmh;
                wf_s[((kt * 4 + nt) * 64 + ln) * 8 + jj] = f2bf(whc[c]);
                wdt_s[hh * D_ + d] = wdc[c];
            }
        }
        __syncthreads();   // W staged (x0 still in flight: syncthreads drains vmcnt,
                           // but x0 are register loads -- the wait IS the stream time,
                           // during which the staging above already executed)

        // (4) persistent registers from staged LDS
        #pragma unroll
        for (int f = 0; f < 16; ++f)
            bfrag[f] = *(const short8_t*)(wf_s + (size_t)(f * 64 + lane) * 8);
        #pragma unroll
        for (int k = 0; k < 4; ++k)
            wsl[k] = *(const float4*)(wdt_s + lane * D_ + wv * 16 + k * 4);

        // (5) batch-0 tproj partial
        {
            float acc = wb;
            #pragma unroll
            for (int k = 0; k < 4; ++k) {
                acc = fmaf(tg0[k].x, wsl[k].x, acc);
                acc = fmaf(tg0[k].y, wsl[k].y, acc);
                acc = fmaf(tg0[k].z, wsl[k].z, acc);
                acc = fmaf(tg0[k].w, wsl[k].w, acc);
            }
            tpp[wv * 64 + lane] = acc;
        }
        __syncthreads();   // bfrag/wsl reads done before hisb[1] is reused

        // (6) convert batch 0 -> hisb[0]
        #pragma unroll
        for (int j = 0; j < 13; ++j) {
            int i = t + j * 512;
            if (i < 6400) {
                int s = i >> 5, d8 = i & 31;
                int pc = (d8 >> 1) ^ (s & 15);
                uint2 v;
                v.x = cvt_pk_bf16(x0[j].x, x0[j].y);
                v.y = cvt_pk_bf16(x0[j].z, x0[j].w);
                *(uint2*)((char*)hisb[0] + s * 256 + pc * 16 + (d8 & 1) * 8) = v;
            }
        }
    }
    __syncthreads();

    // ================= main loop =================
    int cur = 0;
    for (int n = 0; n < KB_; ++n) {
        const int b = b0 + n;
        const bool more = (n + 1 < KB_);
        const unsigned short* hb = hisb[cur];

        // tproj for this batch from LDS partials
        float th[4];
        #pragma unroll
        for (int nt = 0; nt < 4; ++nt) {
            int h = nt * 16 + lm;
            float s0 = tpp[h] + tpp[64 + h] + tpp[128 + h] + tpp[192 + h];
            float s1 = tpp[256 + h] + tpp[320 + h] + tpp[384 + h] + tpp[448 + h];
            th[nt] = s0 + s1;
        }

        // ---- issue next-batch loads (stay in flight across barriers) ----
        float4 x[13];
        float4 tg[4];
        float mkn = 0.f;
        if (more) {
            const float4* hb4n = (const float4*)(his + (size_t)(b + 1) * S_ * D_);
            #pragma unroll
            for (int j = 0; j < 13; ++j) {
                int i = t + j * 512;
                if (i < 6400) x[j] = hb4n[i];
            }
            const float4* tg4 = (const float4*)(target + (size_t)(b + 1) * D_) + wv * 4;
            #pragma unroll
            for (int k = 0; k < 4; ++k) tg[k] = tg4[k];
            if (t < S_) mkn = mask[(size_t)(b + 1) * S_ + t];
        }
        __builtin_amdgcn_sched_barrier(0);   // pin: loads issued before MFMA phase

        // ---- alpha via MFMA: 13 tiles over 8 waves ----
        #pragma unroll
        for (int tt = 0; tt < 2; ++tt) {
            int tile = wv + tt * 8;
            if (tile < 13) {
                int row0 = tile * 16;
                int ar = row0 + lm; if (ar > S_ - 1) ar = S_ - 1;   // clamp pad rows

                f32x4 acc[4];
                #pragma unroll
                for (int nt = 0; nt < 4; ++nt) acc[nt] = (f32x4){0.f, 0.f, 0.f, 0.f};
                #pragma unroll
                for (int kt = 0; kt < 4; ++kt) {
                    int c = (kt * 4 + q) ^ (ar & 15);
                    short8_t av = *(const short8_t*)((const char*)hb + ar * 256 + c * 16);
                    #pragma unroll
                    for (int nt = 0; nt < 4; ++nt)
                        acc[nt] = __builtin_amdgcn_mfma_f32_16x16x32_bf16(av, bfrag[kt * 4 + nt], acc[nt], 0, 0, 0);
                }
                // epilogue: +tproj, relu, dot O (O_bias softmax-invariant)
                float part[4];
                #pragma unroll
                for (int r = 0; r < 4; ++r) {
                    float sum = 0.f;
                    #pragma unroll
                    for (int nt = 0; nt < 4; ++nt) {
                        int h = nt * 16 + lm;
                        float v = acc[nt][r] + th[nt];
                        v = fmaxf(v, 0.f);
                        sum = fmaf(v, ov_s[h], sum);
                    }
                    part[r] = sum;
                }
                #pragma unroll
                for (int off = 1; off < 16; off <<= 1) {
                    #pragma unroll
                    for (int r = 0; r < 4; ++r)
                        part[r] += __shfl_xor(part[r], off);
                }
                if (lm == 0) {
                    #pragma unroll
                    for (int r = 0; r < 4; ++r)
                        alph[row0 + q * 4 + r] = part[r];
                }
            }
        }
        bar();   // A: alpha ready

        // ---- softmax over s = 0..199 (8 waves) ----
        float a = (t < S_) ? alph[t] - mk * MASK_SCALE : -INFINITY;
        float m = a;
        #pragma unroll
        for (int off = 1; off < 64; off <<= 1) m = fmaxf(m, __shfl_xor(m, off));
        if (lane == 0) red8[wv] = m;
        bar();   // B: per-wave maxima ready
        m = red8[0];
        #pragma unroll
        for (int k = 1; k < 8; ++k) m = fmaxf(m, red8[k]);
        float e = (t < S_) ? __expf(a - m) : 0.f;
        if (t < S_) attw[t] = e;
        float ssum = e;
        #pragma unroll
        for (int off = 1; off < 64; off <<= 1) ssum += __shfl_xor(ssum, off);
        if (lane == 0) red8b[wv] = ssum;
        bar();   // C: attw + per-wave sums ready
        float tot = red8b[0];
        #pragma unroll
        for (int k = 1; k < 8; ++k) tot += red8b[k];
        const float inv = 1.f / tot;

        // ---- pooling (current buffer) ----
        const int d8 = t & 31;           // 8B index: d = d8*4 .. d8*4+3
        const int sg = t >> 5;           // 0..15 s-groups
        float acc0 = 0.f, acc1 = 0.f, acc2 = 0.f, acc3 = 0.f;
        #pragma unroll 4
        for (int s = sg; s < S_; s += 16) {
            float w = attw[s];           // half-wave-uniform broadcast
            int pc = (d8 >> 1) ^ (s & 15);
            ushort4_t v = *(const ushort4_t*)((const char*)hb + s * 256 + pc * 16 + (d8 & 1) * 8);
            acc0 = fmaf(w, bf2f(v[0]), acc0);
            acc1 = fmaf(w, bf2f(v[1]), acc1);
            acc2 = fmaf(w, bf2f(v[2]), acc2);
            acc3 = fmaf(w, bf2f(v[3]), acc3);
        }
        acc0 += __shfl_xor(acc0, 32);
        acc1 += __shfl_xor(acc1, 32);
        acc2 += __shfl_xor(acc2, 32);
        acc3 += __shfl_xor(acc3, 32);
        if (wv && lane < 32) {
            float4 p; p.x = acc0; p.y = acc1; p.z = acc2; p.w = acc3;
            *(float4*)(&pool_s[(wv - 1) * D_ + d8 * 4]) = p;
        }

        // ---- convert + write next buffer, next tproj partials ----
        if (more) {
            unsigned short* hn = hisb[cur ^ 1];
            #pragma unroll
            for (int j = 0; j < 13; ++j) {
                int i = t + j * 512;
                if (i < 6400) {
                    int s = i >> 5, d8c = i & 31;
                    int pc = (d8c >> 1) ^ (s & 15);
                    uint2 v;
                    v.x = cvt_pk_bf16(x[j].x, x[j].y);
                    v.y = cvt_pk_bf16(x[j].z, x[j].w);
                    *(uint2*)((char*)hn + s * 256 + pc * 16 + (d8c & 1) * 8) = v;
                }
            }
            float acc = wb;
            #pragma unroll
            for (int k = 0; k < 4; ++k) {
                acc = fmaf(tg[k].x, wsl[k].x, acc);
                acc = fmaf(tg[k].y, wsl[k].y, acc);
                acc = fmaf(tg[k].z, wsl[k].z, acc);
                acc = fmaf(tg[k].w, wsl[k].w, acc);
            }
            tpp[wv * 64 + lane] = acc;
        }
        bar();   // D: pool partials + next buffer + next tpp ready

        if (wv == 0 && lane < 32) {
            #pragma unroll
            for (int k = 0; k < 7; ++k) {
                const float4 p = *(const float4*)(&pool_s[k * D_ + d8 * 4]);
                acc0 += p.x; acc1 += p.y; acc2 += p.z; acc3 += p.w;
            }
            float4 o;
            o.x = acc0 * inv; o.y = acc1 * inv; o.z = acc2 * inv; o.w = acc3 * inv;
            *(float4*)(out + (size_t)b * D_ + d8 * 4) = o;
        }

        mk = mkn;
        cur ^= 1;
    }
}

// ---------------------------------------------------------------------------
extern "C" void kernel_launch(void* const* d_in, const int* in_sizes, int n_in,
                              void* d_out, int out_size, void* d_ws, size_t ws_size,
                              hipStream_t stream) {
    const float* his    = (const float*)d_in[0];
    const float* target = (const float*)d_in[1];
    const float* mask   = (const float*)d_in[2];
    const float* W      = (const float*)d_in[3];
    const float* W_bias = (const float*)d_in[4];
    const float* Ovec   = (const float*)d_in[5];
    // O_bias (d_in[6]) is softmax-invariant -> unused
    float* out = (float*)d_out;

    fused_kernel<<<GRID_, 512, 0, stream>>>(his, mask, target, W, W_bias, Ovec, out);
}